// Round 3
// baseline (322.817 us; speedup 1.0000x reference)
//
#include <hip/hip_runtime.h>

#define IN1 16
#define HIDC 10
#define OUT3 16
#define NTYPES 25
#define MAXB 32
#define HSTR 12   // padded row stride for h1/h2

// ---------------- zero two int regions ----------------
__global__ __launch_bounds__(256) void zero2_kernel(int* __restrict__ a, int na,
                                                    int* __restrict__ b, int nb) {
  int i = blockIdx.x * blockDim.x + threadIdx.x;
  int s = gridDim.x * blockDim.x;
  for (int j = i; j < na; j += s) a[j] = 0;
  for (int j = i; j < nb; j += s) b[j] = 0;
}

// ---------------- histogram + within-bucket rank (1 atomic per edge) ----------
__global__ __launch_bounds__(256) void hist_kernel(const int* __restrict__ edst,
                                                   int* __restrict__ deg,
                                                   int* __restrict__ pos, int E) {
  int e = blockIdx.x * blockDim.x + threadIdx.x;
  if (e < E) pos[e] = atomicAdd(&deg[edst[e]], 1);
}

// ---------------- single-block exclusive scan (int4 vectorized) ----------------
__global__ __launch_bounds__(1024) void scan_kernel(const int4* __restrict__ deg4,
                                                    int* __restrict__ row_ptr, int N) {
  __shared__ int wsums[16];
  __shared__ int s_run;
  int tid = threadIdx.x, lane = tid & 63, wid = tid >> 6;
  if (tid == 0) s_run = 0;
  __syncthreads();
  int N4 = (N + 3) >> 2;
  for (int base = 0; base < N4; base += 1024) {
    int i4 = base + tid;
    int4 v = make_int4(0, 0, 0, 0);
    if (i4 < N4) v = deg4[i4];
    int idx0 = i4 * 4;
    if (idx0 + 1 >= N) v.y = 0;
    if (idx0 + 2 >= N) v.z = 0;
    if (idx0 + 3 >= N) v.w = 0;
    int s = v.x + v.y + v.z + v.w;
    int x = s;
    #pragma unroll
    for (int off = 1; off < 64; off <<= 1) {
      int y = __shfl_up(x, off);
      if (lane >= off) x += y;
    }
    if (lane == 63) wsums[wid] = x;
    __syncthreads();
    if (tid < 16) {
      int w = wsums[tid];
      #pragma unroll
      for (int off = 1; off < 16; off <<= 1) {
        int y = __shfl_up(w, off);
        if (tid >= off) w += y;
      }
      wsums[tid] = w;
    }
    __syncthreads();
    int excl = x - s + ((wid > 0) ? wsums[wid - 1] : 0) + s_run;
    int total = wsums[15];
    if (idx0 < N) row_ptr[idx0] = excl;
    if (idx0 + 1 < N) row_ptr[idx0 + 1] = excl + v.x;
    if (idx0 + 2 < N) row_ptr[idx0 + 2] = excl + v.x + v.y;
    if (idx0 + 3 < N) row_ptr[idx0 + 3] = excl + v.x + v.y + v.z;
    __syncthreads();
    if (tid == 0) s_run += total;
    __syncthreads();
  }
  if (threadIdx.x == 0) row_ptr[N] = s_run;
}

// ---------------- scatter edges into CSR order (plain stores) ----------------
__global__ __launch_bounds__(256) void permute_kernel(
    const int* __restrict__ edst, const int* __restrict__ esrc,
    const int* __restrict__ et, const float2* __restrict__ ef,
    const int* __restrict__ row_ptr, const int* __restrict__ pos,
    int4* __restrict__ edges, int E) {
  int e = blockIdx.x * blockDim.x + threadIdx.x;
  if (e >= E) return;
  int d = edst[e];
  int idx = row_ptr[d] + pos[e];
  float2 f = ef[e];
  int4 r;
  r.x = esrc[e];
  r.y = et[e];
  r.z = __float_as_int(f.x);
  r.w = __float_as_int(f.y);
  edges[idx] = r;
}

// ---------------- precompute ABC coefficients per (type, k) ------------------
// w[e,k] = relu(f0*A[t,k] + f1*B[t,k] + C[t,k])
// A = emb*wh0 + wg0, B = emb*wh1 + wg1, C = emb*bh + bg. Pad rows (i>=IN) = 0.
__global__ __launch_bounds__(256) void abc_pack_kernel(
    const float* __restrict__ emb1, const float* __restrict__ wh1,
    const float* __restrict__ bh1, const float* __restrict__ wg1, const float* __restrict__ bg1,
    const float* __restrict__ emb2, const float* __restrict__ wh2,
    const float* __restrict__ bh2, const float* __restrict__ wg2, const float* __restrict__ bg2,
    const float* __restrict__ emb3, const float* __restrict__ wh3,
    const float* __restrict__ bh3, const float* __restrict__ wg3, const float* __restrict__ bg3,
    float2* __restrict__ gA1, float* __restrict__ gC1,
    float2* __restrict__ gA2, float* __restrict__ gC2,
    float2* __restrict__ gA3, float* __restrict__ gC3)
{
  int t = blockIdx.x;  // 25
  // L1: Dpad = 160 (IN=16, O=10, no pad)
  for (int k = threadIdx.x; k < 160; k += 256) {
    float e = emb1[t * 160 + k];
    gA1[t * 160 + k] = make_float2(fmaf(e, wh1[k], wg1[k]), fmaf(e, wh1[160 + k], wg1[160 + k]));
    gC1[t * 160 + k] = fmaf(e, bh1[k], bg1[k]);
  }
  // L2: Dpad = 120 (IN=10 padded to 12, O=10); k=i*10+o, pad rows k>=100
  for (int k = threadIdx.x; k < 120; k += 256) {
    float a = 0.f, b = 0.f, c = 0.f;
    if (k < 100) {
      float e = emb2[t * 100 + k];
      a = fmaf(e, wh2[k], wg2[k]);
      b = fmaf(e, wh2[100 + k], wg2[100 + k]);
      c = fmaf(e, bh2[k], bg2[k]);
    }
    gA2[t * 120 + k] = make_float2(a, b);
    gC2[t * 120 + k] = c;
  }
  // L3: Dpad = 192 (IN=10 padded to 12, O=16); k=i*16+o, pad rows k>=160
  for (int k = threadIdx.x; k < 192; k += 256) {
    float a = 0.f, b = 0.f, c = 0.f;
    if (k < 160) {
      float e = emb3[t * 160 + k];
      a = fmaf(e, wh3[k], wg3[k]);
      b = fmaf(e, wh3[160 + k], wg3[160 + k]);
      c = fmaf(e, bh3[k], bg3[k]);
    }
    gA3[t * 192 + k] = make_float2(a, b);
    gC3[t * 192 + k] = c;
  }
}

// ---------------- fused gather layer ----------------
// Wave layout: slot (NPW nodes/wave) x ig (IPG i-groups) x o (16 output lanes).
// IC = XSTR/IPG input channels per lane. Cross-ig reduce via shfl_xor.
template<int IN_C, int XSTR, int O, int IPG, int NPW, bool POOL>
__global__ __launch_bounds__(256) void layer_kernel(
    const float* __restrict__ xin,      // [N, XSTR]
    const int4* __restrict__ edges,     // CSR by dst: {src, type, f0, f1}
    const int* __restrict__ row_ptr,    // [N+1]
    const float2* __restrict__ gA2,     // [25*Dpad] {A,B}
    const float* __restrict__ gC,       // [25*Dpad]
    const float* __restrict__ root,     // [IN_C, O]
    const float* __restrict__ bias,     // [O]
    float* __restrict__ hout,           // [N, HSTR], or psum[B*16] if POOL
    const int* __restrict__ ctype, const int* __restrict__ bids,
    float* __restrict__ pcnt, int N, int B)
{
  constexpr int Dpad = XSTR * O;
  constexpr int IC = XSTR / IPG;
  __shared__ __align__(16) float2 s_A[NTYPES * Dpad];
  __shared__ __align__(16) float s_C[NTYPES * Dpad];
  __shared__ float s_root[IN_C * O];
  __shared__ float s_bias[O];
  __shared__ float s_psum[POOL ? (MAXB * 16) : 1];
  __shared__ float s_pcnt[POOL ? MAXB : 1];

  int tid = threadIdx.x;
  {
    const float4* ga = (const float4*)gA2;
    float4* sa = (float4*)s_A;
    for (int k = tid; k < NTYPES * Dpad / 2; k += 256) sa[k] = ga[k];
    const float4* gc = (const float4*)gC;
    float4* sc = (float4*)s_C;
    for (int k = tid; k < NTYPES * Dpad / 4; k += 256) sc[k] = gc[k];
    for (int k = tid; k < IN_C * O; k += 256) s_root[k] = root[k];
    if (tid < O) s_bias[tid] = bias[tid];
    if (POOL) {
      for (int i = tid; i < MAXB * 16; i += 256) s_psum[i] = 0.f;
      for (int i = tid; i < MAXB; i += 256) s_pcnt[i] = 0.f;
    }
  }
  __syncthreads();

  int wave = tid >> 6, lane = tid & 63;
  int slot = lane / (16 * IPG);
  int rem = lane % (16 * IPG);
  int ig = rem >> 4;
  int o = rem & 15;
  int oc = (o < O) ? o : (O - 1);
  int kbase0 = (ig * IC) * O + oc;

  int n0 = (blockIdx.x * 4 + wave) * NPW + slot;
  int nstride = gridDim.x * 4 * NPW;
  for (int n = n0; n < N; n += nstride) {
    int start = row_ptr[n], end = row_ptr[n + 1];
    float acc = 0.f;
    int4 r = (start < end) ? edges[start] : make_int4(0, 0, 0, 0);
    for (int e = start; e < end;) {
      int4 cur = r;
      ++e;
      if (e < end) r = edges[e];          // prefetch next edge record
      int src = cur.x, t = cur.y;
      float f0 = __int_as_float(cur.z), f1 = __int_as_float(cur.w);
      const float* __restrict__ xr = xin + (size_t)src * XSTR + ig * IC;
      float xv[IC];
      if (IC == 4) {
        float4 v = *(const float4*)xr;
        xv[0] = v.x; xv[1] = v.y; xv[2] = v.z; xv[3] = v.w;
      } else {  // IC == 6, 8B-aligned
        const float2* x2 = (const float2*)xr;
        float2 a = x2[0], b = x2[1], c = x2[2];
        xv[0] = a.x; xv[1] = a.y; xv[2] = b.x; xv[3] = b.y; xv[4] = c.x; xv[5] = c.y;
      }
      int kb = t * Dpad + kbase0;
      #pragma unroll
      for (int j = 0; j < IC; ++j) {
        int k = kb + j * O;
        float2 ab = s_A[k];
        float c = s_C[k];
        float w = fmaxf(fmaf(f0, ab.x, fmaf(f1, ab.y, c)), 0.f);
        acc = fmaf(xv[j], w, acc);
      }
    }
    // reduce across ig groups (ig = lane bit4 [,bit5])
    acc += __shfl_xor(acc, 16);
    if (IPG == 4) acc += __shfl_xor(acc, 32);

    if (ig == 0 && o < O) {
      float inv = 1.0f / fmaxf((float)(end - start), 1.0f);
      float v = fmaf(acc, inv, s_bias[o]);
      const float* __restrict__ xr = xin + (size_t)n * XSTR;
      #pragma unroll
      for (int i = 0; i < IN_C; ++i) v = fmaf(xr[i], s_root[i * O + o], v);
      v = fmaxf(v, 0.f);
      if (!POOL) {
        hout[(size_t)n * HSTR + o] = v;
      } else if (ctype[n] == 1) {
        int b = bids[n];
        atomicAdd(&s_psum[b * 16 + o], v);
        if (o == 0) atomicAdd(&s_pcnt[b], 1.0f);
      }
    }
  }

  if (POOL) {
    __syncthreads();
    for (int i = tid; i < B * 16; i += 256) {
      float v = s_psum[i];
      if (v != 0.f) atomicAdd(&hout[i], v);
    }
    for (int i = tid; i < B; i += 256) {
      float c = s_pcnt[i];
      if (c != 0.f) atomicAdd(&pcnt[i], c);
    }
  }
}

__global__ __launch_bounds__(256) void finalize_kernel(
    const float* __restrict__ psum, const float* __restrict__ pcnt,
    float* __restrict__ out, int B) {
  int i = blockIdx.x * blockDim.x + threadIdx.x;
  if (i >= B * OUT3) return;
  int b = i / OUT3;
  out[i] = psum[i] / fmaxf(pcnt[b], 1.0f);
}

// ---------------- launch ----------------
extern "C" void kernel_launch(void* const* d_in, const int* in_sizes, int n_in,
                              void* d_out, int out_size, void* d_ws, size_t ws_size,
                              hipStream_t stream)
{
  const float* x     = (const float*)d_in[0];
  const float* ef    = (const float*)d_in[1];
  const int*   et    = (const int*)d_in[2];
  const int*   esrc  = (const int*)d_in[3];
  const int*   edst  = (const int*)d_in[4];
  const int*   ctype = (const int*)d_in[5];
  const int*   bids  = (const int*)d_in[6];
  const float* emb1 = (const float*)d_in[8];
  const float* wh1  = (const float*)d_in[9];
  const float* bh1  = (const float*)d_in[10];
  const float* wg1  = (const float*)d_in[11];
  const float* bg1  = (const float*)d_in[12];
  const float* root1= (const float*)d_in[13];
  const float* bias1= (const float*)d_in[14];
  const float* emb2 = (const float*)d_in[15];
  const float* wh2  = (const float*)d_in[16];
  const float* bh2  = (const float*)d_in[17];
  const float* wg2  = (const float*)d_in[18];
  const float* bg2  = (const float*)d_in[19];
  const float* root2= (const float*)d_in[20];
  const float* bias2= (const float*)d_in[21];
  const float* emb3 = (const float*)d_in[22];
  const float* wh3  = (const float*)d_in[23];
  const float* bh3  = (const float*)d_in[24];
  const float* wg3  = (const float*)d_in[25];
  const float* bg3  = (const float*)d_in[26];
  const float* root3= (const float*)d_in[27];
  const float* bias3= (const float*)d_in[28];

  const int N = in_sizes[0] / IN1;
  const int E = in_sizes[2];
  const int B = out_size / OUT3;

  // workspace layout (all section sizes multiples of 4 floats -> 16B aligned)
  int4* edges   = (int4*)d_ws;                       // E recs
  int*  deg     = (int*)(edges + E);                 // N
  int*  pos     = deg + N;                           // E
  int*  row_ptr = pos + E;                           // N+1 (padded)
  int   np1r    = ((N + 1 + 3) / 4) * 4;
  float* h1     = (float*)(row_ptr + np1r);          // N*HSTR
  float* h2     = h1 + (size_t)N * HSTR;             // N*HSTR
  float* psum   = h2 + (size_t)N * HSTR;             // B*16
  float* pcnt   = psum + (size_t)B * 16;             // B
  float* pk     = pcnt + B;
  float2* gA1 = (float2*)pk;                         // 25*160 f2 = 8000 f
  float*  gC1 = pk + 8000;                           // 4000
  float2* gA2 = (float2*)(pk + 12000);               // 25*120 f2 = 6000 f
  float*  gC2 = pk + 18000;                          // 3000
  float2* gA3 = (float2*)(pk + 21000);               // 25*192 f2 = 9600 f
  float*  gC3 = pk + 30600;                          // 4800

  zero2_kernel<<<128, 256, 0, stream>>>(deg, N, (int*)psum, B * 16 + B);
  abc_pack_kernel<<<NTYPES, 256, 0, stream>>>(
      emb1, wh1, bh1, wg1, bg1, emb2, wh2, bh2, wg2, bg2, emb3, wh3, bh3, wg3, bg3,
      gA1, gC1, gA2, gC2, gA3, gC3);
  hist_kernel<<<(E + 255) / 256, 256, 0, stream>>>(edst, deg, pos, E);
  scan_kernel<<<1, 1024, 0, stream>>>((const int4*)deg, row_ptr, N);
  permute_kernel<<<(E + 255) / 256, 256, 0, stream>>>(
      edst, esrc, et, (const float2*)ef, row_ptr, pos, edges, E);

  // L1: IN=16 (XSTR=16), O=10, whole wave per node (IPG=4, NPW=1)
  layer_kernel<IN1, 16, HIDC, 4, 1, false><<<1024, 256, 0, stream>>>(
      x, edges, row_ptr, gA1, gC1, root1, bias1, h1, nullptr, nullptr, nullptr, N, B);
  // L2: IN=10 (XSTR=12), O=10, 2 nodes/wave (IPG=2, NPW=2)
  layer_kernel<HIDC, HSTR, HIDC, 2, 2, false><<<1024, 256, 0, stream>>>(
      h1, edges, row_ptr, gA2, gC2, root2, bias2, h2, nullptr, nullptr, nullptr, N, B);
  // L3: IN=10 (XSTR=12), O=16, 2 nodes/wave, fused pooling
  layer_kernel<HIDC, HSTR, OUT3, 2, 2, true><<<1024, 256, 0, stream>>>(
      h2, edges, row_ptr, gA3, gC3, root3, bias3, psum, ctype, bids, pcnt, N, B);

  finalize_kernel<<<1, 256, 0, stream>>>(psum, pcnt, (float*)d_out, B);
}

// Round 4
// 301.379 us; speedup vs baseline: 1.0711x; 1.0711x over previous
//
#include <hip/hip_runtime.h>

#define IN1 16
#define HIDC 10
#define OUT3 16
#define NTYPES 25
#define MAXB 32
#define HSTR 12   // padded row stride for h1/h2

// ---------------- zero two int regions ----------------
__global__ __launch_bounds__(256) void zero2_kernel(int* __restrict__ a, int na,
                                                    int* __restrict__ b, int nb) {
  int i = blockIdx.x * blockDim.x + threadIdx.x;
  int s = gridDim.x * blockDim.x;
  for (int j = i; j < na; j += s) a[j] = 0;
  for (int j = i; j < nb; j += s) b[j] = 0;
}

// ---------------- histogram + within-bucket rank (1 atomic per edge) ----------
__global__ __launch_bounds__(256) void hist_kernel(const int* __restrict__ edst,
                                                   int* __restrict__ deg,
                                                   int* __restrict__ pos, int E) {
  int e = blockIdx.x * blockDim.x + threadIdx.x;
  if (e < E) pos[e] = atomicAdd(&deg[edst[e]], 1);
}

// ---------------- single-block exclusive scan (int4 vectorized) ----------------
__global__ __launch_bounds__(1024) void scan_kernel(const int4* __restrict__ deg4,
                                                    int* __restrict__ row_ptr, int N) {
  __shared__ int wsums[16];
  __shared__ int s_run;
  int tid = threadIdx.x, lane = tid & 63, wid = tid >> 6;
  if (tid == 0) s_run = 0;
  __syncthreads();
  int N4 = (N + 3) >> 2;
  for (int base = 0; base < N4; base += 1024) {
    int i4 = base + tid;
    int4 v = make_int4(0, 0, 0, 0);
    if (i4 < N4) v = deg4[i4];
    int idx0 = i4 * 4;
    if (idx0 + 1 >= N) v.y = 0;
    if (idx0 + 2 >= N) v.z = 0;
    if (idx0 + 3 >= N) v.w = 0;
    int s = v.x + v.y + v.z + v.w;
    int x = s;
    #pragma unroll
    for (int off = 1; off < 64; off <<= 1) {
      int y = __shfl_up(x, off);
      if (lane >= off) x += y;
    }
    if (lane == 63) wsums[wid] = x;
    __syncthreads();
    if (tid < 16) {
      int w = wsums[tid];
      #pragma unroll
      for (int off = 1; off < 16; off <<= 1) {
        int y = __shfl_up(w, off);
        if (tid >= off) w += y;
      }
      wsums[tid] = w;
    }
    __syncthreads();
    int excl = x - s + ((wid > 0) ? wsums[wid - 1] : 0) + s_run;
    int total = wsums[15];
    if (idx0 < N) row_ptr[idx0] = excl;
    if (idx0 + 1 < N) row_ptr[idx0 + 1] = excl + v.x;
    if (idx0 + 2 < N) row_ptr[idx0 + 2] = excl + v.x + v.y;
    if (idx0 + 3 < N) row_ptr[idx0 + 3] = excl + v.x + v.y + v.z;
    __syncthreads();
    if (tid == 0) s_run += total;
    __syncthreads();
  }
  if (threadIdx.x == 0) row_ptr[N] = s_run;
}

// ---------------- scatter edges into CSR order (plain stores) ----------------
__global__ __launch_bounds__(256) void permute_kernel(
    const int* __restrict__ edst, const int* __restrict__ esrc,
    const int* __restrict__ et, const float2* __restrict__ ef,
    const int* __restrict__ row_ptr, const int* __restrict__ pos,
    int4* __restrict__ edges, int E) {
  int e = blockIdx.x * blockDim.x + threadIdx.x;
  if (e >= E) return;
  int d = edst[e];
  int idx = row_ptr[d] + pos[e];
  float2 f = ef[e];
  int4 r;
  r.x = esrc[e];
  r.y = et[e];
  r.z = __float_as_int(f.x);
  r.w = __float_as_int(f.y);
  edges[idx] = r;
}

// ---------------- precompute ABC, paired-i layout ------------------
// w[e,k] = relu(f0*A[t,k] + f1*B[t,k] + C[t,k]);  A=emb*wh0+wg0, B=emb*wh1+wg1, C=emb*bh+bg
// AB4[(i2*25+t)*O + o] = {A(2i2,o), B(2i2,o), A(2i2+1,o), B(2i2+1,o)}
// C2 [(i2*25+t)*O + o] = {C(2i2,o), C(2i2+1,o)};  pad rows i>=IN_C are zero.
template<int IN_C, int XSTR, int O>
__device__ void pack_one(int t, const float* emb, const float* wh, const float* bh,
                         const float* wg, const float* bg,
                         float4* gAB, float2* gC) {
  constexpr int D = IN_C * O;
  constexpr int NI2 = XSTR / 2;
  for (int idx = threadIdx.x; idx < NI2 * O; idx += 256) {
    int i2 = idx / O, o = idx - i2 * O;
    int i0 = 2 * i2, i1 = 2 * i2 + 1;
    float a0 = 0.f, b0 = 0.f, c0 = 0.f, a1 = 0.f, b1 = 0.f, c1 = 0.f;
    if (i0 < IN_C) {
      int k = i0 * O + o;
      float e = emb[t * D + k];
      a0 = fmaf(e, wh[k], wg[k]);
      b0 = fmaf(e, wh[D + k], wg[D + k]);
      c0 = fmaf(e, bh[k], bg[k]);
    }
    if (i1 < IN_C) {
      int k = i1 * O + o;
      float e = emb[t * D + k];
      a1 = fmaf(e, wh[k], wg[k]);
      b1 = fmaf(e, wh[D + k], wg[D + k]);
      c1 = fmaf(e, bh[k], bg[k]);
    }
    int kk = (i2 * NTYPES + t) * O + o;
    gAB[kk] = make_float4(a0, b0, a1, b1);
    gC[kk] = make_float2(c0, c1);
  }
}

__global__ __launch_bounds__(256) void abc_pack_kernel(
    const float* __restrict__ emb1, const float* __restrict__ wh1,
    const float* __restrict__ bh1, const float* __restrict__ wg1, const float* __restrict__ bg1,
    const float* __restrict__ emb2, const float* __restrict__ wh2,
    const float* __restrict__ bh2, const float* __restrict__ wg2, const float* __restrict__ bg2,
    const float* __restrict__ emb3, const float* __restrict__ wh3,
    const float* __restrict__ bh3, const float* __restrict__ wg3, const float* __restrict__ bg3,
    float4* __restrict__ gAB1, float2* __restrict__ gC1,
    float4* __restrict__ gAB2, float2* __restrict__ gC2,
    float4* __restrict__ gAB3, float2* __restrict__ gC3)
{
  int t = blockIdx.x;  // 25
  pack_one<IN1, 16, HIDC>(t, emb1, wh1, bh1, wg1, bg1, gAB1, gC1);
  pack_one<HIDC, HSTR, HIDC>(t, emb2, wh2, bh2, wg2, bg2, gAB2, gC2);
  pack_one<HIDC, HSTR, OUT3>(t, emb3, wh3, bh3, wg3, bg3, gAB3, gC3);
}

// ---------------- fused gather layer ----------------
// Wave: slot (NPW nodes) x ig (IPG i-groups) x o (16). IC = XSTR/IPG per lane.
template<int IN_C, int XSTR, int O, int IPG, int NPW, bool POOL>
__global__ __launch_bounds__(512, 6) void layer_kernel(
    const float* __restrict__ xin,      // [N, XSTR]
    const int4* __restrict__ edges,     // CSR by dst: {src, type, f0, f1}
    const int* __restrict__ row_ptr,    // [N+1]
    const float4* __restrict__ gAB,     // [NI2*25*O]
    const float2* __restrict__ gC,      // [NI2*25*O]
    const float* __restrict__ root,     // [IN_C, O]
    const float* __restrict__ bias,     // [O]
    float* __restrict__ hout,           // [N, HSTR], or psum[B*16] if POOL
    const int* __restrict__ ctype, const int* __restrict__ bids,
    float* __restrict__ pcnt, int N, int B)
{
  constexpr int NI2 = XSTR / 2;
  constexpr int SZ = NI2 * NTYPES * O;
  constexpr int IC = XSTR / IPG;
  constexpr int NPB = 8 * NPW;          // 8 waves/block
  __shared__ __align__(16) float4 s_AB[SZ];
  __shared__ __align__(16) float2 s_C[SZ];
  __shared__ float s_root[IN_C * O];
  __shared__ float s_bias[O];
  __shared__ float s_psum[POOL ? (MAXB * 16) : 1];
  __shared__ float s_pcnt[POOL ? MAXB : 1];

  int tid = threadIdx.x;
  for (int k = tid; k < SZ; k += 512) s_AB[k] = gAB[k];
  {
    const float4* gc4 = (const float4*)gC;
    float4* sc4 = (float4*)s_C;
    for (int k = tid; k < SZ / 2; k += 512) sc4[k] = gc4[k];
  }
  for (int k = tid; k < IN_C * O; k += 512) s_root[k] = root[k];
  if (tid < O) s_bias[tid] = bias[tid];
  if (POOL) {
    for (int i = tid; i < MAXB * 16; i += 512) s_psum[i] = 0.f;
    for (int i = tid; i < MAXB; i += 512) s_pcnt[i] = 0.f;
  }
  __syncthreads();

  int wave = tid >> 6, lane = tid & 63;
  int slot = lane / (16 * IPG);
  int rem = lane % (16 * IPG);
  int ig = rem >> 4;
  int o = rem & 15;
  int oc = (o < O) ? o : (O - 1);

  int n = blockIdx.x * NPB + wave * NPW + slot;
  int start = 0, end = 0;
  if (n < N) { start = row_ptr[n]; end = row_ptr[n + 1]; }
  float acc = 0.f;
  int4 r = (start < end) ? edges[start] : make_int4(0, 0, 0, 0);
  for (int e = start; e < end;) {
    int4 cur = r;
    ++e;
    if (e < end) r = edges[e];          // prefetch next edge record
    int src = cur.x, t = cur.y;
    float f0 = __int_as_float(cur.z), f1 = __int_as_float(cur.w);
    const float* __restrict__ xr = xin + (size_t)src * XSTR + ig * IC;
    float xv[IC];
    if (IC == 4) {
      float4 v = *(const float4*)xr;
      xv[0] = v.x; xv[1] = v.y; xv[2] = v.z; xv[3] = v.w;
    } else {  // IC == 6
      const float2* x2 = (const float2*)xr;
      float2 a = x2[0], b = x2[1], c = x2[2];
      xv[0] = a.x; xv[1] = a.y; xv[2] = b.x; xv[3] = b.y; xv[4] = c.x; xv[5] = c.y;
    }
    #pragma unroll
    for (int j = 0; j < IC / 2; ++j) {
      int i2 = ig * (IC / 2) + j;
      int k = (i2 * NTYPES + t) * O + oc;
      float4 ab = s_AB[k];
      float2 c2 = s_C[k];
      float w0 = fmaxf(fmaf(f0, ab.x, fmaf(f1, ab.y, c2.x)), 0.f);
      float w1 = fmaxf(fmaf(f0, ab.z, fmaf(f1, ab.w, c2.y)), 0.f);
      acc = fmaf(xv[2 * j], w0, acc);
      acc = fmaf(xv[2 * j + 1], w1, acc);
    }
  }
  // reduce across ig groups
  acc += __shfl_xor(acc, 16);
  if (IPG == 4) acc += __shfl_xor(acc, 32);

  if (n < N && ig == 0 && o < O) {
    float inv = 1.0f / fmaxf((float)(end - start), 1.0f);
    float v = fmaf(acc, inv, s_bias[o]);
    const float* __restrict__ xr = xin + (size_t)n * XSTR;
    #pragma unroll
    for (int i = 0; i < IN_C; ++i) v = fmaf(xr[i], s_root[i * O + o], v);
    v = fmaxf(v, 0.f);
    if (!POOL) {
      hout[(size_t)n * HSTR + o] = v;
    } else if (ctype[n] == 1) {
      int b = bids[n];
      atomicAdd(&s_psum[b * 16 + o], v);
      if (o == 0) atomicAdd(&s_pcnt[b], 1.0f);
    }
  }

  if (POOL) {
    __syncthreads();
    for (int i = tid; i < B * 16; i += 512) {
      float v = s_psum[i];
      if (v != 0.f) atomicAdd(&hout[i], v);
    }
    for (int i = tid; i < B; i += 512) {
      float c = s_pcnt[i];
      if (c != 0.f) atomicAdd(&pcnt[i], c);
    }
  }
}

__global__ __launch_bounds__(256) void finalize_kernel(
    const float* __restrict__ psum, const float* __restrict__ pcnt,
    float* __restrict__ out, int B) {
  int i = blockIdx.x * blockDim.x + threadIdx.x;
  if (i >= B * OUT3) return;
  int b = i / OUT3;
  out[i] = psum[i] / fmaxf(pcnt[b], 1.0f);
}

// ---------------- launch ----------------
extern "C" void kernel_launch(void* const* d_in, const int* in_sizes, int n_in,
                              void* d_out, int out_size, void* d_ws, size_t ws_size,
                              hipStream_t stream)
{
  const float* x     = (const float*)d_in[0];
  const float* ef    = (const float*)d_in[1];
  const int*   et    = (const int*)d_in[2];
  const int*   esrc  = (const int*)d_in[3];
  const int*   edst  = (const int*)d_in[4];
  const int*   ctype = (const int*)d_in[5];
  const int*   bids  = (const int*)d_in[6];
  const float* emb1 = (const float*)d_in[8];
  const float* wh1  = (const float*)d_in[9];
  const float* bh1  = (const float*)d_in[10];
  const float* wg1  = (const float*)d_in[11];
  const float* bg1  = (const float*)d_in[12];
  const float* root1= (const float*)d_in[13];
  const float* bias1= (const float*)d_in[14];
  const float* emb2 = (const float*)d_in[15];
  const float* wh2  = (const float*)d_in[16];
  const float* bh2  = (const float*)d_in[17];
  const float* wg2  = (const float*)d_in[18];
  const float* bg2  = (const float*)d_in[19];
  const float* root2= (const float*)d_in[20];
  const float* bias2= (const float*)d_in[21];
  const float* emb3 = (const float*)d_in[22];
  const float* wh3  = (const float*)d_in[23];
  const float* bh3  = (const float*)d_in[24];
  const float* wg3  = (const float*)d_in[25];
  const float* bg3  = (const float*)d_in[26];
  const float* root3= (const float*)d_in[27];
  const float* bias3= (const float*)d_in[28];

  const int N = in_sizes[0] / IN1;
  const int E = in_sizes[2];
  const int B = out_size / OUT3;

  // workspace layout (all sections 16B aligned)
  int4* edges   = (int4*)d_ws;                       // E recs
  int*  deg     = (int*)(edges + E);                 // N
  int*  pos     = deg + N;                           // E
  int*  row_ptr = pos + E;                           // N+1 (padded)
  int   np1r    = ((N + 1 + 3) / 4) * 4;
  float* h1     = (float*)(row_ptr + np1r);          // N*HSTR
  float* h2     = h1 + (size_t)N * HSTR;             // N*HSTR
  float* psum   = h2 + (size_t)N * HSTR;             // B*16
  float* pcnt   = psum + (size_t)B * 16;             // B
  float* pk     = pcnt + B;
  float4* gAB1 = (float4*)pk;                        // 2000 f4 = 8000 f
  float2* gC1  = (float2*)(pk + 8000);               // 2000 f2 = 4000 f
  float4* gAB2 = (float4*)(pk + 12000);              // 1500 f4 = 6000 f
  float2* gC2  = (float2*)(pk + 18000);              // 1500 f2 = 3000 f
  float4* gAB3 = (float4*)(pk + 21000);              // 2400 f4 = 9600 f
  float2* gC3  = (float2*)(pk + 30600);              // 2400 f2 = 4800 f

  zero2_kernel<<<128, 256, 0, stream>>>(deg, N, (int*)psum, B * 16 + B);
  abc_pack_kernel<<<NTYPES, 256, 0, stream>>>(
      emb1, wh1, bh1, wg1, bg1, emb2, wh2, bh2, wg2, bg2, emb3, wh3, bh3, wg3, bg3,
      gAB1, gC1, gAB2, gC2, gAB3, gC3);
  hist_kernel<<<(E + 255) / 256, 256, 0, stream>>>(edst, deg, pos, E);
  scan_kernel<<<1, 1024, 0, stream>>>((const int4*)deg, row_ptr, N);
  permute_kernel<<<(E + 255) / 256, 256, 0, stream>>>(
      edst, esrc, et, (const float2*)ef, row_ptr, pos, edges, E);

  // L1: whole wave per node (IPG=4, NPW=1): 8 nodes/block
  layer_kernel<IN1, 16, HIDC, 4, 1, false><<<(N + 7) / 8, 512, 0, stream>>>(
      x, edges, row_ptr, gAB1, gC1, root1, bias1, h1, nullptr, nullptr, nullptr, N, B);
  // L2: IPG=2, NPW=2: 16 nodes/block
  layer_kernel<HIDC, HSTR, HIDC, 2, 2, false><<<(N + 15) / 16, 512, 0, stream>>>(
      h1, edges, row_ptr, gAB2, gC2, root2, bias2, h2, nullptr, nullptr, nullptr, N, B);
  // L3: IPG=2, NPW=2, fused pooling
  layer_kernel<HIDC, HSTR, OUT3, 2, 2, true><<<(N + 15) / 16, 512, 0, stream>>>(
      h2, edges, row_ptr, gAB3, gC3, root3, bias3, psum, ctype, bids, pcnt, N, B);

  finalize_kernel<<<1, 256, 0, stream>>>(psum, pcnt, (float*)d_out, B);
}